// Round 1
// baseline (946.647 us; speedup 1.0000x reference)
//
#include <hip/hip_runtime.h>

typedef _Float16 f16;
typedef _Float16 f16x8 __attribute__((ext_vector_type(8)));
typedef _Float16 f16x4 __attribute__((ext_vector_type(4)));
typedef float    f32x4 __attribute__((ext_vector_type(4)));

#define GLD16(g, l)                                                            \
  __builtin_amdgcn_global_load_lds(                                            \
      (const __attribute__((address_space(1))) void*)(g),                      \
      (__attribute__((address_space(3))) void*)(l), 16, 0, 0)

// ---------------------------------------------------------------- cast f32->f16
__global__ __launch_bounds__(256) void cast_f32_f16(
    const float* __restrict__ in, f16* __restrict__ out, int n4) {
  int i = blockIdx.x * 256 + threadIdx.x;
  if (i >= n4) return;
  float4 f = reinterpret_cast<const float4*>(in)[i];
  f16x4 h = {(f16)f.x, (f16)f.y, (f16)f.z, (f16)f.w};
  reinterpret_cast<f16x4*>(out)[i] = h;
}

// ---------------------------------------------------------------- TN GEMM
// C[m,n] = sum_k A[m,k] * B[n,k]   (both operands K-major, m97 structure)
// MODE 0: f16 out, + bias[n]                       (Q, K projections)
// MODE 1: f16 out transposed per-batch -> Vt[b][n][s], + bias[n]   (V)
// MODE 2: f32 out, * scale + mask[n]               (scores)
// MODE 3: f32 out plain                            (PV -> context)
template <int MODE>
__global__ __launch_bounds__(256) void gemm_tn(
    const f16* __restrict__ A, const f16* __restrict__ Bm,
    void* __restrict__ C, const float* __restrict__ aux, float scale,
    int K, int lda, int ldb, int ldc) {
  __shared__ __attribute__((aligned(16))) f16 sA[128 * 32];
  __shared__ __attribute__((aligned(16))) f16 sB[128 * 32];

  const int tid   = threadIdx.x;
  const int tileM = blockIdx.y * 128;
  const int tileN = blockIdx.x * 128;
  const int wave  = tid >> 6, lane = tid & 63;
  const int wm = (wave >> 1) * 64, wn = (wave & 1) * 64;
  const int quad = lane >> 4, lrow = lane & 15;

  f32x4 acc[4][4] = {};

  const f16* gA = A + (size_t)tileM * lda;
  const f16* gB = Bm + (size_t)tileN * ldb;

  for (int k0 = 0; k0 < K; k0 += 32) {
#pragma unroll
    for (int i = 0; i < 2; ++i) {
      int id = i * 256 + tid;
      int r = id >> 2, c = (id & 3) * 8;
      GLD16(gA + (size_t)r * lda + k0 + c, &sA[id * 8]);
      GLD16(gB + (size_t)r * ldb + k0 + c, &sB[id * 8]);
    }
    __syncthreads();
    f16x8 af[4], bf[4];
#pragma unroll
    for (int x = 0; x < 4; ++x) {
      af[x] = *reinterpret_cast<const f16x8*>(&sA[(wm + x * 16 + lrow) * 32 + quad * 8]);
      bf[x] = *reinterpret_cast<const f16x8*>(&sB[(wn + x * 16 + lrow) * 32 + quad * 8]);
    }
#pragma unroll
    for (int x = 0; x < 4; ++x)
#pragma unroll
      for (int y = 0; y < 4; ++y)
        acc[x][y] = __builtin_amdgcn_mfma_f32_16x16x32_f16(af[x], bf[y], acc[x][y], 0, 0, 0);
    __syncthreads();
  }

#pragma unroll
  for (int x = 0; x < 4; ++x)
#pragma unroll
    for (int y = 0; y < 4; ++y)
#pragma unroll
      for (int r = 0; r < 4; ++r) {
        int m = tileM + wm + x * 16 + quad * 4 + r;
        int n = tileN + wn + y * 16 + lrow;
        float v = acc[x][y][r];
        if (MODE == 0) {
          ((f16*)C)[(size_t)m * ldc + n] = (f16)(v + aux[n]);
        } else if (MODE == 1) {
          int b = m >> 12, s = m & 4095;  // S = 4096
          ((f16*)C)[(size_t)b * (2048u * 4096u) + (size_t)n * 4096 + s] = (f16)(v + aux[n]);
        } else if (MODE == 2) {
          ((float*)C)[(size_t)m * ldc + n] = v * scale + aux[n];
        } else {
          ((float*)C)[(size_t)m * ldc + n] = v;
        }
      }
}

// ------------------------------------------------- softmax over 4096 fp32, in-place -> f16 probs
// One block per row. Reads full row into registers, writes f16 probs to the
// same row start (row stride becomes 8192 f16 elements for the PV GEMM).
__global__ __launch_bounds__(256) void softmax_inplace(float* __restrict__ sc) {
  const int tid = threadIdx.x;
  float* rp = sc + (size_t)blockIdx.x * 4096;
  float4 v[4];
#pragma unroll
  for (int j = 0; j < 4; ++j) v[j] = reinterpret_cast<float4*>(rp)[tid + j * 256];

  float m = -1e30f;
#pragma unroll
  for (int j = 0; j < 4; ++j)
    m = fmaxf(m, fmaxf(fmaxf(v[j].x, v[j].y), fmaxf(v[j].z, v[j].w)));
#pragma unroll
  for (int off = 32; off; off >>= 1) m = fmaxf(m, __shfl_xor(m, off));

  __shared__ float red[8];
  int wave = tid >> 6, lane = tid & 63;
  if (lane == 0) red[wave] = m;
  __syncthreads();
  m = fmaxf(fmaxf(red[0], red[1]), fmaxf(red[2], red[3]));

  float s = 0.f;
#pragma unroll
  for (int j = 0; j < 4; ++j) {
    v[j].x = __expf(v[j].x - m); s += v[j].x;
    v[j].y = __expf(v[j].y - m); s += v[j].y;
    v[j].z = __expf(v[j].z - m); s += v[j].z;
    v[j].w = __expf(v[j].w - m); s += v[j].w;
  }
#pragma unroll
  for (int off = 32; off; off >>= 1) s += __shfl_xor(s, off);
  if (lane == 0) red[4 + wave] = s;
  __syncthreads();
  s = red[4] + red[5] + red[6] + red[7];
  float inv = 1.0f / s;

  f16* op = reinterpret_cast<f16*>(rp);
#pragma unroll
  for (int j = 0; j < 4; ++j) {
    f16x4 h = {(f16)(v[j].x * inv), (f16)(v[j].y * inv),
               (f16)(v[j].z * inv), (f16)(v[j].w * inv)};
    reinterpret_cast<f16x4*>(op)[tid + j * 256] = h;
  }
}

// ---------------------------------------------------------------- launch
extern "C" void kernel_launch(void* const* d_in, const int* in_sizes, int n_in,
                              void* d_out, int out_size, void* d_ws, size_t ws_size,
                              hipStream_t stream) {
  const float* hs   = (const float*)d_in[0];
  const float* mask = (const float*)d_in[1];
  const float* Wq   = (const float*)d_in[2];
  const float* bq   = (const float*)d_in[3];
  const float* Wk   = (const float*)d_in[4];
  const float* bk   = (const float*)d_in[5];
  const float* Wv   = (const float*)d_in[6];
  const float* bv   = (const float*)d_in[7];
  float* out = (float*)d_out;

  const int B = 2, S = 4096, H = 2048;

  // workspace layout (226.5 MB total)
  f16* hs_h = (f16*)d_ws;                      // B*S*H
  f16* w_h  = hs_h + (size_t)B * S * H;        // 3*H*H
  f16* Qh   = w_h + (size_t)3 * H * H;         // B*S*H
  f16* Kh   = Qh + (size_t)B * S * H;          // B*S*H
  f16* Vt   = Kh + (size_t)B * S * H;          // B*H*S (transposed)
  float* Sc = (float*)(Vt + (size_t)B * S * H);// S*S fp32, reused per batch

  int n4 = B * S * H / 4;
  cast_f32_f16<<<(n4 + 255) / 256, 256, 0, stream>>>(hs, hs_h, n4);
  n4 = H * H / 4;
  cast_f32_f16<<<(n4 + 255) / 256, 256, 0, stream>>>(Wq, w_h, n4);
  cast_f32_f16<<<(n4 + 255) / 256, 256, 0, stream>>>(Wk, w_h + (size_t)H * H, n4);
  cast_f32_f16<<<(n4 + 255) / 256, 256, 0, stream>>>(Wv, w_h + (size_t)2 * H * H, n4);

  dim3 blk(256);
  dim3 g_qkv(H / 128, B * S / 128);  // (16, 64)
  gemm_tn<0><<<g_qkv, blk, 0, stream>>>(hs_h, w_h, Qh, bq, 1.f, H, H, H, H);
  gemm_tn<0><<<g_qkv, blk, 0, stream>>>(hs_h, w_h + (size_t)H * H, Kh, bk, 1.f, H, H, H, H);
  gemm_tn<1><<<g_qkv, blk, 0, stream>>>(hs_h, w_h + (size_t)2 * H * H, Vt, bv, 1.f, H, H, H, 0);

  const float sscale = 0.088388347648318447f;  // 1/sqrt(HEAD_SIZE=128)
  for (int b = 0; b < B; ++b) {
    dim3 g_sc(S / 128, S / 128);  // (32, 32)
    gemm_tn<2><<<g_sc, blk, 0, stream>>>(Qh + (size_t)b * S * H, Kh + (size_t)b * S * H,
                                         Sc, mask + (size_t)b * S, sscale, H, H, H, S);
    softmax_inplace<<<S, 256, 0, stream>>>(Sc);
    dim3 g_pv(H / 128, S / 128);  // (16, 32)
    gemm_tn<3><<<g_pv, blk, 0, stream>>>((const f16*)Sc, Vt + (size_t)b * H * S,
                                         out + (size_t)b * S * H, nullptr, 1.f,
                                         S, 2 * S, S, H);
  }
}

// Round 2
// 898.509 us; speedup vs baseline: 1.0536x; 1.0536x over previous
//
#include <hip/hip_runtime.h>

typedef _Float16 f16;
typedef _Float16 f16x8 __attribute__((ext_vector_type(8)));
typedef _Float16 f16x4 __attribute__((ext_vector_type(4)));
typedef float    f32x4 __attribute__((ext_vector_type(4)));

#define GLD16(g, l)                                                            \
  __builtin_amdgcn_global_load_lds(                                            \
      (const __attribute__((address_space(1))) void*)(g),                      \
      (__attribute__((address_space(3))) void*)(l), 16, 0, 0)

static constexpr int S = 4096, H = 2048, B = 2;

// ---------------------------------------------------------------- cast f32->f16
__global__ __launch_bounds__(256) void cast_f32_f16(
    const float* __restrict__ in, f16* __restrict__ out, int n4) {
  int i = blockIdx.x * 256 + threadIdx.x;
  if (i >= n4) return;
  float4 f = reinterpret_cast<const float4*>(in)[i];
  f16x4 h = {(f16)f.x, (f16)f.y, (f16)f.z, (f16)f.w};
  reinterpret_cast<f16x4*>(out)[i] = h;
}

// ---------------------------------------------------------------- TN GEMM
// C[m,n] = sum_k A[m,k]*B[n,k], 128x128 tile, BK=32, m97 structure.
// MODE 0: fused QKV.  A=hs_h [8192,2048], B=Wcat [6144,2048].
//         n<2048 -> Q(+bq) f16; n<4096 -> K(+bk) f16; else -> Vt[b][h][s](+bv) f16
// MODE 2: scores, batched. A=Qh[m][h], B=Kh per batch. out f16 v*scale+mask[b][n]
// MODE 3: PV, batched. A=Sc16[m][k], B=Vt per batch. out f32 to d_out.
template <int MODE>
__global__ __launch_bounds__(256) void gemm_tn(
    const f16* __restrict__ A, const f16* __restrict__ Bm,
    void* __restrict__ C0, void* __restrict__ C1, void* __restrict__ C2,
    const float* __restrict__ x0, const float* __restrict__ x1,
    const float* __restrict__ x2, float scale, int K, int lda, int ldb) {
  __shared__ __attribute__((aligned(16))) f16 sA[128 * 32];
  __shared__ __attribute__((aligned(16))) f16 sB[128 * 32];

  const int tid   = threadIdx.x;
  const int tileM = blockIdx.y * 128;
  const int tileN = blockIdx.x * 128;
  const int wave  = tid >> 6, lane = tid & 63;
  const int wm = (wave >> 1) * 64, wn = (wave & 1) * 64;
  const int quad = lane >> 4, lrow = lane & 15;

  f32x4 acc[4][4] = {};

  // batch-aware operand row bases (tiles never straddle batches: S%128==0)
  size_t rowA = tileM, rowB = tileN;
  if (MODE == 2) rowB = (size_t)(tileM >> 12) * S + tileN;  // Kh row = b*S + k
  if (MODE == 3) rowB = (size_t)(tileM >> 12) * H + tileN;  // Vt row = b*H + h

  const f16* gA = A + rowA * lda;
  const f16* gB = Bm + rowB * ldb;

  for (int k0 = 0; k0 < K; k0 += 32) {
#pragma unroll
    for (int i = 0; i < 2; ++i) {
      int id = i * 256 + tid;
      int r = id >> 2, c = (id & 3) * 8;
      GLD16(gA + (size_t)r * lda + k0 + c, &sA[id * 8]);
      GLD16(gB + (size_t)r * ldb + k0 + c, &sB[id * 8]);
    }
    __syncthreads();
    f16x8 af[4], bf[4];
#pragma unroll
    for (int x = 0; x < 4; ++x) {
      af[x] = *reinterpret_cast<const f16x8*>(&sA[(wm + x * 16 + lrow) * 32 + quad * 8]);
      bf[x] = *reinterpret_cast<const f16x8*>(&sB[(wn + x * 16 + lrow) * 32 + quad * 8]);
    }
#pragma unroll
    for (int x = 0; x < 4; ++x)
#pragma unroll
      for (int y = 0; y < 4; ++y)
        acc[x][y] = __builtin_amdgcn_mfma_f32_16x16x32_f16(af[x], bf[y], acc[x][y], 0, 0, 0);
    __syncthreads();
  }

#pragma unroll
  for (int x = 0; x < 4; ++x)
#pragma unroll
    for (int y = 0; y < 4; ++y)
#pragma unroll
      for (int r = 0; r < 4; ++r) {
        int m = tileM + wm + x * 16 + quad * 4 + r;
        int n = tileN + wn + y * 16 + lrow;
        float v = acc[x][y][r];
        if (MODE == 0) {
          int seg = n >> 11, nn = n & 2047;  // uniform per tile (2048%128==0)
          if (seg == 0) {
            ((f16*)C0)[(size_t)m * H + nn] = (f16)(v + x0[nn]);
          } else if (seg == 1) {
            ((f16*)C1)[(size_t)m * H + nn] = (f16)(v + x1[nn]);
          } else {
            int b = m >> 12, s = m & (S - 1);
            ((f16*)C2)[(size_t)b * H * S + (size_t)nn * S + s] = (f16)(v + x2[nn]);
          }
        } else if (MODE == 2) {
          int b = m >> 12;
          ((f16*)C0)[(size_t)m * S + n] = (f16)(v * scale + x0[(size_t)b * S + n]);
        } else {
          ((float*)C0)[(size_t)m * H + n] = v;
        }
      }
}

// ------------------------------------------------- softmax over 4096 f16, in place
__global__ __launch_bounds__(256) void softmax_f16(f16* __restrict__ sc) {
  const int tid = threadIdx.x;
  f16* rp = sc + (size_t)blockIdx.x * S;
  f16x8 h[2];
#pragma unroll
  for (int j = 0; j < 2; ++j) h[j] = reinterpret_cast<f16x8*>(rp)[tid + j * 256];

  float v[16];
#pragma unroll
  for (int j = 0; j < 2; ++j)
#pragma unroll
    for (int e = 0; e < 8; ++e) v[j * 8 + e] = (float)h[j][e];

  float m = -1e30f;
#pragma unroll
  for (int e = 0; e < 16; ++e) m = fmaxf(m, v[e]);
#pragma unroll
  for (int off = 32; off; off >>= 1) m = fmaxf(m, __shfl_xor(m, off));

  __shared__ float red[8];
  int wave = tid >> 6, lane = tid & 63;
  if (lane == 0) red[wave] = m;
  __syncthreads();
  m = fmaxf(fmaxf(red[0], red[1]), fmaxf(red[2], red[3]));

  float s = 0.f;
#pragma unroll
  for (int e = 0; e < 16; ++e) { v[e] = __expf(v[e] - m); s += v[e]; }
#pragma unroll
  for (int off = 32; off; off >>= 1) s += __shfl_xor(s, off);
  if (lane == 0) red[4 + wave] = s;
  __syncthreads();
  s = red[4] + red[5] + red[6] + red[7];
  float inv = 1.0f / s;

#pragma unroll
  for (int j = 0; j < 2; ++j) {
#pragma unroll
    for (int e = 0; e < 8; ++e) h[j][e] = (f16)(v[j * 8 + e] * inv);
    reinterpret_cast<f16x8*>(rp)[tid + j * 256] = h[j];
  }
}

// ---------------------------------------------------------------- launch
extern "C" void kernel_launch(void* const* d_in, const int* in_sizes, int n_in,
                              void* d_out, int out_size, void* d_ws, size_t ws_size,
                              hipStream_t stream) {
  const float* hs   = (const float*)d_in[0];
  const float* mask = (const float*)d_in[1];
  const float* Wq   = (const float*)d_in[2];
  const float* bq   = (const float*)d_in[3];
  const float* Wk   = (const float*)d_in[4];
  const float* bk   = (const float*)d_in[5];
  const float* Wv   = (const float*)d_in[6];
  const float* bv   = (const float*)d_in[7];
  float* out = (float*)d_out;

  // workspace layout (~226 MB)
  f16* hs_h = (f16*)d_ws;                        // B*S*H        (33.5 MB)
  f16* w_h  = hs_h + (size_t)B * S * H;          // 3*H*H concat (25.2 MB)
  f16* Qh   = w_h + (size_t)3 * H * H;           // B*S*H
  f16* Kh   = Qh + (size_t)B * S * H;            // B*S*H
  f16* Vt   = Kh + (size_t)B * S * H;            // B*H*S (transposed)
  f16* Sc   = Vt + (size_t)B * S * H;            // B*S*S f16    (67 MB)

  int n4 = B * S * H / 4;
  cast_f32_f16<<<(n4 + 255) / 256, 256, 0, stream>>>(hs, hs_h, n4);
  n4 = H * H / 4;
  cast_f32_f16<<<(n4 + 255) / 256, 256, 0, stream>>>(Wq, w_h, n4);
  cast_f32_f16<<<(n4 + 255) / 256, 256, 0, stream>>>(Wk, w_h + (size_t)H * H, n4);
  cast_f32_f16<<<(n4 + 255) / 256, 256, 0, stream>>>(Wv, w_h + (size_t)2 * H * H, n4);

  dim3 blk(256);
  const float sscale = 0.088388347648318447f;  // 1/sqrt(HEAD_SIZE=128)

  // fused QKV: [8192 x 6144] = hs_h [8192x2048] @ Wcat^T, grid 48x64 = 3072 blocks
  gemm_tn<0><<<dim3(3 * H / 128, B * S / 128), blk, 0, stream>>>(
      hs_h, w_h, Qh, Kh, Vt, bq, bk, bv, 1.f, H, H, H);

  // scores both batches: grid 32x64 = 2048 blocks
  gemm_tn<2><<<dim3(S / 128, B * S / 128), blk, 0, stream>>>(
      Qh, Kh, Sc, nullptr, nullptr, mask, nullptr, nullptr, sscale, H, H, H);

  softmax_f16<<<B * S, 256, 0, stream>>>(Sc);

  // PV both batches: grid 16x64 = 1024 blocks
  gemm_tn<3><<<dim3(H / 128, B * S / 128), blk, 0, stream>>>(
      Sc, Vt, out, nullptr, nullptr, nullptr, nullptr, nullptr, 1.f, S, S, S);
}

// Round 3
// 788.616 us; speedup vs baseline: 1.2004x; 1.1393x over previous
//
#include <hip/hip_runtime.h>

typedef _Float16 f16;
typedef _Float16 f16x8 __attribute__((ext_vector_type(8)));
typedef _Float16 f16x4 __attribute__((ext_vector_type(4)));
typedef float    f32x4 __attribute__((ext_vector_type(4)));

#define GLD16(g, l)                                                            \
  __builtin_amdgcn_global_load_lds(                                            \
      (const __attribute__((address_space(1))) void*)(g),                      \
      (__attribute__((address_space(3))) void*)(l), 16, 0, 0)

static constexpr int S = 4096, H = 2048, B = 2;

// ---------------------------------------------------------------- cast f32->f16
__global__ __launch_bounds__(256) void cast_f32_f16(
    const float* __restrict__ in, f16* __restrict__ out, int n4) {
  int i = blockIdx.x * 256 + threadIdx.x;
  if (i >= n4) return;
  float4 f = reinterpret_cast<const float4*>(in)[i];
  f16x4 h = {(f16)f.x, (f16)f.y, (f16)f.z, (f16)f.w};
  reinterpret_cast<f16x4*>(out)[i] = h;
}

// ---------------------------------------------------------------- TN GEMM
// C[m,n] = sum_k A[m,k]*B[n,k], 128x128 tile, BK=64, xor-swizzled LDS,
// GROUP_M=8 raster, 1D grid of tilesM*tilesN blocks.
// MODE 0: fused QKV.  n<2048 -> Q(+bq) f16; <4096 -> K(+bk); else Vt[b][h][s](+bv)
// MODE 2: scores, batched. f16 out = v*scale + mask[b][n]
// MODE 3: PV, batched. f32 out.
template <int MODE>
__global__ __launch_bounds__(256) void gemm_tn(
    const f16* __restrict__ A, const f16* __restrict__ Bm,
    void* __restrict__ C0, void* __restrict__ C1, void* __restrict__ C2,
    const float* __restrict__ x0, const float* __restrict__ x1,
    const float* __restrict__ x2, float scale, int K, int lda, int ldb,
    int tilesM, int tilesN) {
  __shared__ __attribute__((aligned(16))) f16 sA[128 * 64];
  __shared__ __attribute__((aligned(16))) f16 sB[128 * 64];

  // GROUP_M=8 supergroup raster for L2 locality (tilesM % 8 == 0 always here)
  const int pid = blockIdx.x;
  const int nig = 8 * tilesN;
  const int first_m = (pid / nig) * 8;
  const int pid_m = first_m + ((pid % nig) & 7);
  const int pid_n = (pid % nig) >> 3;
  const int tileM = pid_m * 128;
  const int tileN = pid_n * 128;

  const int tid  = threadIdx.x;
  const int wave = tid >> 6, lane = tid & 63;
  const int wm = (wave >> 1) * 64, wn = (wave & 1) * 64;
  const int quad = lane >> 4, lrow = lane & 15;

  f32x4 acc[4][4] = {};

  // batch-aware operand row bases (tiles never straddle batches: S%128==0)
  size_t rowA = tileM, rowB = tileN;
  if (MODE == 2) rowB = (size_t)(tileM >> 12) * S + tileN;  // Kh row = b*S + k
  if (MODE == 3) rowB = (size_t)(tileM >> 12) * H + tileN;  // Vt row = b*H + h
  const f16* gA = A + rowA * lda;
  const f16* gB = Bm + rowB * ldb;

  // staging: 128 rows x 8 chunks(16B); chunk stored at source col (c ^ (r&7))
  size_t aoff[4], boff[4];
  int ldsoff[4];
#pragma unroll
  for (int j = 0; j < 4; ++j) {
    int id = j * 256 + tid;
    int r = id >> 3, cs = (id & 7) ^ (r & 7);
    aoff[j] = (size_t)r * lda + cs * 8;
    boff[j] = (size_t)r * ldb + cs * 8;
    ldsoff[j] = id * 8;
  }

  for (int k0 = 0; k0 < K; k0 += 64) {
#pragma unroll
    for (int j = 0; j < 4; ++j) {
      GLD16(gA + aoff[j] + k0, &sA[ldsoff[j]]);
      GLD16(gB + boff[j] + k0, &sB[ldsoff[j]]);
    }
    __syncthreads();
#pragma unroll
    for (int kk = 0; kk < 2; ++kk) {
      f16x8 af[4], bf[4];
      const int ch = kk * 4 + quad;
      const int pos = (ch ^ (lrow & 7)) * 8;  // xor-unswizzle (row&7 == lrow&7)
#pragma unroll
      for (int x = 0; x < 4; ++x) {
        af[x] = *reinterpret_cast<const f16x8*>(&sA[(wm + x * 16 + lrow) * 64 + pos]);
        bf[x] = *reinterpret_cast<const f16x8*>(&sB[(wn + x * 16 + lrow) * 64 + pos]);
      }
#pragma unroll
      for (int x = 0; x < 4; ++x)
#pragma unroll
        for (int y = 0; y < 4; ++y)
          acc[x][y] = __builtin_amdgcn_mfma_f32_16x16x32_f16(af[x], bf[y], acc[x][y], 0, 0, 0);
    }
    __syncthreads();
  }

#pragma unroll
  for (int x = 0; x < 4; ++x)
#pragma unroll
    for (int y = 0; y < 4; ++y)
#pragma unroll
      for (int r = 0; r < 4; ++r) {
        int m = tileM + wm + x * 16 + quad * 4 + r;
        int n = tileN + wn + y * 16 + lrow;
        float v = acc[x][y][r];
        if (MODE == 0) {
          int seg = n >> 11, nn = n & 2047;  // uniform per tile
          if (seg == 0) {
            ((f16*)C0)[(size_t)m * H + nn] = (f16)(v + x0[nn]);
          } else if (seg == 1) {
            ((f16*)C1)[(size_t)m * H + nn] = (f16)(v + x1[nn]);
          } else {
            int b = m >> 12, s = m & (S - 1);
            ((f16*)C2)[(size_t)b * H * S + (size_t)nn * S + s] = (f16)(v + x2[nn]);
          }
        } else if (MODE == 2) {
          int b = m >> 12;
          ((f16*)C0)[(size_t)m * S + n] = (f16)(v * scale + x0[(size_t)b * S + n]);
        } else {
          ((float*)C0)[(size_t)m * H + n] = v;
        }
      }
}

// ------------------------------------------------- softmax over 4096 f16, in place
__global__ __launch_bounds__(256) void softmax_f16(f16* __restrict__ sc) {
  const int tid = threadIdx.x;
  f16* rp = sc + (size_t)blockIdx.x * S;
  f16x8 h[2];
#pragma unroll
  for (int j = 0; j < 2; ++j) h[j] = reinterpret_cast<f16x8*>(rp)[tid + j * 256];

  float v[16];
#pragma unroll
  for (int j = 0; j < 2; ++j)
#pragma unroll
    for (int e = 0; e < 8; ++e) v[j * 8 + e] = (float)h[j][e];

  float m = -1e30f;
#pragma unroll
  for (int e = 0; e < 16; ++e) m = fmaxf(m, v[e]);
#pragma unroll
  for (int off = 32; off; off >>= 1) m = fmaxf(m, __shfl_xor(m, off));

  __shared__ float red[8];
  int wave = tid >> 6, lane = tid & 63;
  if (lane == 0) red[wave] = m;
  __syncthreads();
  m = fmaxf(fmaxf(red[0], red[1]), fmaxf(red[2], red[3]));

  float s = 0.f;
#pragma unroll
  for (int e = 0; e < 16; ++e) { v[e] = __expf(v[e] - m); s += v[e]; }
#pragma unroll
  for (int off = 32; off; off >>= 1) s += __shfl_xor(s, off);
  if (lane == 0) red[4 + wave] = s;
  __syncthreads();
  s = red[4] + red[5] + red[6] + red[7];
  float inv = 1.0f / s;

#pragma unroll
  for (int j = 0; j < 2; ++j) {
#pragma unroll
    for (int e = 0; e < 8; ++e) h[j][e] = (f16)(v[j * 8 + e] * inv);
    reinterpret_cast<f16x8*>(rp)[tid + j * 256] = h[j];
  }
}

// ---------------------------------------------------------------- launch
extern "C" void kernel_launch(void* const* d_in, const int* in_sizes, int n_in,
                              void* d_out, int out_size, void* d_ws, size_t ws_size,
                              hipStream_t stream) {
  const float* hs   = (const float*)d_in[0];
  const float* mask = (const float*)d_in[1];
  const float* Wq   = (const float*)d_in[2];
  const float* bq   = (const float*)d_in[3];
  const float* Wk   = (const float*)d_in[4];
  const float* bk   = (const float*)d_in[5];
  const float* Wv   = (const float*)d_in[6];
  const float* bv   = (const float*)d_in[7];
  float* out = (float*)d_out;

  // workspace layout (~226 MB)
  f16* hs_h = (f16*)d_ws;                        // B*S*H
  f16* w_h  = hs_h + (size_t)B * S * H;          // 3*H*H concat
  f16* Qh   = w_h + (size_t)3 * H * H;           // B*S*H
  f16* Kh   = Qh + (size_t)B * S * H;            // B*S*H
  f16* Vt   = Kh + (size_t)B * S * H;            // B*H*S (transposed)
  f16* Sc   = Vt + (size_t)B * S * H;            // B*S*S f16

  int n4 = B * S * H / 4;
  cast_f32_f16<<<(n4 + 255) / 256, 256, 0, stream>>>(hs, hs_h, n4);
  n4 = H * H / 4;
  cast_f32_f16<<<(n4 + 255) / 256, 256, 0, stream>>>(Wq, w_h, n4);
  cast_f32_f16<<<(n4 + 255) / 256, 256, 0, stream>>>(Wk, w_h + (size_t)H * H, n4);
  cast_f32_f16<<<(n4 + 255) / 256, 256, 0, stream>>>(Wv, w_h + (size_t)2 * H * H, n4);

  dim3 blk(256);
  const float sscale = 0.088388347648318447f;  // 1/sqrt(HEAD_SIZE=128)

  // fused QKV: M=8192, N=6144, K=2048. tilesM=64, tilesN=48
  gemm_tn<0><<<dim3(64 * 48), blk, 0, stream>>>(
      hs_h, w_h, Qh, Kh, Vt, bq, bk, bv, 1.f, H, H, H, 64, 48);

  // scores both batches: M=8192, N=4096, K=2048. tilesM=64, tilesN=32
  gemm_tn<2><<<dim3(64 * 32), blk, 0, stream>>>(
      Qh, Kh, Sc, nullptr, nullptr, mask, nullptr, nullptr, sscale, H, H, H, 64, 32);

  softmax_f16<<<B * S, 256, 0, stream>>>(Sc);

  // PV both batches: M=8192, N=2048, K=4096. tilesM=64, tilesN=16
  gemm_tn<3><<<dim3(64 * 16), blk, 0, stream>>>(
      Sc, Vt, out, nullptr, nullptr, nullptr, nullptr, nullptr, 1.f, S, S, S, 64, 16);
}

// Round 4
// 758.674 us; speedup vs baseline: 1.2478x; 1.0395x over previous
//
#include <hip/hip_runtime.h>

typedef _Float16 f16;
typedef _Float16 f16x8 __attribute__((ext_vector_type(8)));
typedef _Float16 f16x4 __attribute__((ext_vector_type(4)));
typedef float    f32x4 __attribute__((ext_vector_type(4)));

#define GLD16(g, l)                                                            \
  __builtin_amdgcn_global_load_lds(                                            \
      (const __attribute__((address_space(1))) void*)(g),                      \
      (__attribute__((address_space(3))) void*)(l), 16, 0, 0)

static constexpr int S = 4096, H = 2048, B = 2;

// ---------------------------------------------------------------- casts
__global__ __launch_bounds__(256) void cast_f32_f16(
    const float* __restrict__ in, f16* __restrict__ out, int n4) {
  int i = blockIdx.x * 256 + threadIdx.x;
  if (i >= n4) return;
  float4 f = reinterpret_cast<const float4*>(in)[i];
  f16x4 h = {(f16)f.x, (f16)f.y, (f16)f.z, (f16)f.w};
  reinterpret_cast<f16x4*>(out)[i] = h;
}

// one launch casting Wq|Wk|Wv into the concatenated w_h buffer
__global__ __launch_bounds__(256) void cast_w3(
    const float* __restrict__ w0, const float* __restrict__ w1,
    const float* __restrict__ w2, f16* __restrict__ out) {
  const int per = H * H / 4;  // float4 groups per weight
  int i = blockIdx.x * 256 + threadIdx.x;
  int seg = i / per, off = i - seg * per;
  const float* src = seg == 0 ? w0 : (seg == 1 ? w1 : w2);
  float4 f = reinterpret_cast<const float4*>(src)[off];
  f16x4 h = {(f16)f.x, (f16)f.y, (f16)f.z, (f16)f.w};
  reinterpret_cast<f16x4*>(out)[i] = h;
}

// ---------------------------------------------------------------- TN GEMM
// C[m,n] = sum_k A[m,k]*B[n,k], 128x128 tile, BK=64, xor-swizzled LDS.
// 2D grid: blockIdx.x = N-tile (fastest -> XCD c owns N-tiles = c mod 8,
// keeping that XCD's B panels L2-resident), blockIdx.y = M-tile.
// MODE 0: fused QKV.  n<2048 -> Q(+bq) f16; <4096 -> K(+bk); else Vt[b][h][s](+bv)
// MODE 2: scores, batched. f16 out = v*scale + mask[b][n]
// MODE 3: PV, batched. f32 out.
template <int MODE>
__global__ __launch_bounds__(256) void gemm_tn(
    const f16* __restrict__ A, const f16* __restrict__ Bm,
    void* __restrict__ C0, void* __restrict__ C1, void* __restrict__ C2,
    const float* __restrict__ x0, const float* __restrict__ x1,
    const float* __restrict__ x2, float scale, int K, int lda, int ldb) {
  __shared__ __attribute__((aligned(16))) f16 sA[128 * 64];
  __shared__ __attribute__((aligned(16))) f16 sB[128 * 64];

  const int tileM = blockIdx.y * 128;
  const int tileN = blockIdx.x * 128;

  const int tid  = threadIdx.x;
  const int wave = tid >> 6, lane = tid & 63;
  const int wm = (wave >> 1) * 64, wn = (wave & 1) * 64;
  const int quad = lane >> 4, lrow = lane & 15;

  f32x4 acc[4][4] = {};

  // batch-aware operand row bases (tiles never straddle batches: S%128==0)
  size_t rowA = tileM, rowB = tileN;
  if (MODE == 2) rowB = (size_t)(tileM >> 12) * S + tileN;  // Kh row = b*S + k
  if (MODE == 3) rowB = (size_t)(tileM >> 12) * H + tileN;  // Vt row = b*H + h
  const f16* gA = A + rowA * lda;
  const f16* gB = Bm + rowB * ldb;

  // staging: 128 rows x 8 chunks(16B); chunk stored at source col (c ^ (r&7))
  size_t aoff[4], boff[4];
  int ldsoff[4];
#pragma unroll
  for (int j = 0; j < 4; ++j) {
    int id = j * 256 + tid;
    int r = id >> 3, cs = (id & 7) ^ (r & 7);
    aoff[j] = (size_t)r * lda + cs * 8;
    boff[j] = (size_t)r * ldb + cs * 8;
    ldsoff[j] = id * 8;
  }

  for (int k0 = 0; k0 < K; k0 += 64) {
#pragma unroll
    for (int j = 0; j < 4; ++j) {
      GLD16(gA + aoff[j] + k0, &sA[ldsoff[j]]);
      GLD16(gB + boff[j] + k0, &sB[ldsoff[j]]);
    }
    __syncthreads();
#pragma unroll
    for (int kk = 0; kk < 2; ++kk) {
      f16x8 af[4], bf[4];
      const int ch = kk * 4 + quad;
      const int pos = (ch ^ (lrow & 7)) * 8;  // xor-unswizzle (row&7 == lrow&7)
#pragma unroll
      for (int x = 0; x < 4; ++x) {
        af[x] = *reinterpret_cast<const f16x8*>(&sA[(wm + x * 16 + lrow) * 64 + pos]);
        bf[x] = *reinterpret_cast<const f16x8*>(&sB[(wn + x * 16 + lrow) * 64 + pos]);
      }
#pragma unroll
      for (int x = 0; x < 4; ++x)
#pragma unroll
        for (int y = 0; y < 4; ++y)
          acc[x][y] = __builtin_amdgcn_mfma_f32_16x16x32_f16(af[x], bf[y], acc[x][y], 0, 0, 0);
    }
    __syncthreads();
  }

#pragma unroll
  for (int x = 0; x < 4; ++x)
#pragma unroll
    for (int y = 0; y < 4; ++y)
#pragma unroll
      for (int r = 0; r < 4; ++r) {
        int m = tileM + wm + x * 16 + quad * 4 + r;
        int n = tileN + wn + y * 16 + lrow;
        float v = acc[x][y][r];
        if (MODE == 0) {
          int seg = n >> 11, nn = n & 2047;  // uniform per tile
          if (seg == 0) {
            ((f16*)C0)[(size_t)m * H + nn] = (f16)(v + x0[nn]);
          } else if (seg == 1) {
            ((f16*)C1)[(size_t)m * H + nn] = (f16)(v + x1[nn]);
          } else {
            int b = m >> 12, s = m & (S - 1);
            ((f16*)C2)[(size_t)b * H * S + (size_t)nn * S + s] = (f16)(v + x2[nn]);
          }
        } else if (MODE == 2) {
          int b = m >> 12;
          ((f16*)C0)[(size_t)m * S + n] = (f16)(v * scale + x0[(size_t)b * S + n]);
        } else {
          ((float*)C0)[(size_t)m * H + n] = v;
        }
      }
}

// ------------------------------------------------- softmax over 4096 f16, in place
__global__ __launch_bounds__(256) void softmax_f16(f16* __restrict__ sc) {
  const int tid = threadIdx.x;
  f16* rp = sc + (size_t)blockIdx.x * S;
  f16x8 h[2];
#pragma unroll
  for (int j = 0; j < 2; ++j) h[j] = reinterpret_cast<f16x8*>(rp)[tid + j * 256];

  float v[16];
#pragma unroll
  for (int j = 0; j < 2; ++j)
#pragma unroll
    for (int e = 0; e < 8; ++e) v[j * 8 + e] = (float)h[j][e];

  float m = -1e30f;
#pragma unroll
  for (int e = 0; e < 16; ++e) m = fmaxf(m, v[e]);
#pragma unroll
  for (int off = 32; off; off >>= 1) m = fmaxf(m, __shfl_xor(m, off));

  __shared__ float red[8];
  int wave = tid >> 6, lane = tid & 63;
  if (lane == 0) red[wave] = m;
  __syncthreads();
  m = fmaxf(fmaxf(red[0], red[1]), fmaxf(red[2], red[3]));

  float s = 0.f;
#pragma unroll
  for (int e = 0; e < 16; ++e) { v[e] = __expf(v[e] - m); s += v[e]; }
#pragma unroll
  for (int off = 32; off; off >>= 1) s += __shfl_xor(s, off);
  if (lane == 0) red[4 + wave] = s;
  __syncthreads();
  s = red[4] + red[5] + red[6] + red[7];
  float inv = 1.0f / s;

#pragma unroll
  for (int j = 0; j < 2; ++j) {
#pragma unroll
    for (int e = 0; e < 8; ++e) h[j][e] = (f16)(v[j * 8 + e] * inv);
    reinterpret_cast<f16x8*>(rp)[tid + j * 256] = h[j];
  }
}

// ---------------------------------------------------------------- launch
extern "C" void kernel_launch(void* const* d_in, const int* in_sizes, int n_in,
                              void* d_out, int out_size, void* d_ws, size_t ws_size,
                              hipStream_t stream) {
  const float* hs   = (const float*)d_in[0];
  const float* mask = (const float*)d_in[1];
  const float* Wq   = (const float*)d_in[2];
  const float* bq   = (const float*)d_in[3];
  const float* Wk   = (const float*)d_in[4];
  const float* bk   = (const float*)d_in[5];
  const float* Wv   = (const float*)d_in[6];
  const float* bv   = (const float*)d_in[7];
  float* out = (float*)d_out;

  // workspace layout (~226 MB)
  f16* hs_h = (f16*)d_ws;                        // B*S*H
  f16* w_h  = hs_h + (size_t)B * S * H;          // 3*H*H concat
  f16* Qh   = w_h + (size_t)3 * H * H;           // B*S*H
  f16* Kh   = Qh + (size_t)B * S * H;            // B*S*H
  f16* Vt   = Kh + (size_t)B * S * H;            // B*H*S (transposed)
  f16* Sc   = Vt + (size_t)B * S * H;            // B*S*S f16

  int n4 = B * S * H / 4;
  cast_f32_f16<<<(n4 + 255) / 256, 256, 0, stream>>>(hs, hs_h, n4);
  cast_w3<<<(3 * H * H / 4) / 256, 256, 0, stream>>>(Wq, Wk, Wv, w_h);

  dim3 blk(256);
  const float sscale = 0.088388347648318447f;  // 1/sqrt(HEAD_SIZE=128)

  // fused QKV: M=8192, N=6144, K=2048. grid (48,64), x fastest
  gemm_tn<0><<<dim3(48, 64), blk, 0, stream>>>(
      hs_h, w_h, Qh, Kh, Vt, bq, bk, bv, 1.f, H, H, H);

  // scores both batches: M=8192, N=4096, K=2048. grid (32,64)
  gemm_tn<2><<<dim3(32, 64), blk, 0, stream>>>(
      Qh, Kh, Sc, nullptr, nullptr, mask, nullptr, nullptr, sscale, H, H, H);

  softmax_f16<<<B * S, 256, 0, stream>>>(Sc);

  // PV both batches: M=8192, N=2048, K=4096. grid (16,64)
  gemm_tn<3><<<dim3(16, 64), blk, 0, stream>>>(
      Sc, Vt, out, nullptr, nullptr, nullptr, nullptr, nullptr, 1.f, S, S, S);
}

// Round 5
// 726.252 us; speedup vs baseline: 1.3035x; 1.0446x over previous
//
#include <hip/hip_runtime.h>

typedef _Float16 f16;
typedef _Float16 f16x8 __attribute__((ext_vector_type(8)));
typedef _Float16 f16x4 __attribute__((ext_vector_type(4)));
typedef float    f32x4 __attribute__((ext_vector_type(4)));

#define GLD16(g, l)                                                            \
  __builtin_amdgcn_global_load_lds(                                            \
      (const __attribute__((address_space(1))) void*)(g),                      \
      (__attribute__((address_space(3))) void*)(l), 16, 0, 0)

static constexpr int S = 4096, H = 2048, B = 2;

// ------------------------------------------- single fused cast: hs | Wq|Wk|Wv
__global__ __launch_bounds__(256) void cast_all(
    const float* __restrict__ hs, const float* __restrict__ w0,
    const float* __restrict__ w1, const float* __restrict__ w2,
    f16* __restrict__ hs_h, f16* __restrict__ w_h) {
  const int hsN4 = B * S * H / 4;  // float4 groups in hs
  const int wN4  = H * H / 4;     // float4 groups per weight
  int i = blockIdx.x * 256 + threadIdx.x;
  float4 f;
  if (i < hsN4) {
    f = reinterpret_cast<const float4*>(hs)[i];
    f16x4 h = {(f16)f.x, (f16)f.y, (f16)f.z, (f16)f.w};
    reinterpret_cast<f16x4*>(hs_h)[i] = h;
  } else {
    int j = i - hsN4;
    int seg = j / wN4, off = j - seg * wN4;
    const float* src = seg == 0 ? w0 : (seg == 1 ? w1 : w2);
    f = reinterpret_cast<const float4*>(src)[off];
    f16x4 h = {(f16)f.x, (f16)f.y, (f16)f.z, (f16)f.w};
    reinterpret_cast<f16x4*>(w_h)[j] = h;
  }
}

// ---------------------------------------------------------------- TN GEMM
// C[m,n] = sum_k A[m,k]*B[n,k], 128x128 tile, BK=64, xor-swizzled LDS.
// 2D grid, x = N-tile fastest (XCD c owns N-tiles c mod 8 -> B panels L2-resident).
// MODE 0: fused QKV.  n<2048 -> Q(+bq) f16; <4096 -> K(+bk); else Vt[b][h][s](+bv)
//         (V tile bounced through LDS for full-cacheline coalesced stores)
// MODE 2: scores, batched. f16 out = v*scale + mask[b][n]
// MODE 3: PV, batched. f32 out.
template <int MODE>
__global__ __launch_bounds__(256) void gemm_tn(
    const f16* __restrict__ A, const f16* __restrict__ Bm,
    void* __restrict__ C0, void* __restrict__ C1, void* __restrict__ C2,
    const float* __restrict__ x0, const float* __restrict__ x1,
    const float* __restrict__ x2, float scale, int K, int lda, int ldb) {
  // K-loop needs 2x16384; MODE 0 V-epilogue needs 128*136*2 = 34816
  constexpr int SMEM_BYTES = (MODE == 0) ? 34816 : 32768;
  __shared__ __attribute__((aligned(16))) char smem[SMEM_BYTES];
  f16* sA = (f16*)smem;
  f16* sB = (f16*)(smem + 16384);

  const int tileM = blockIdx.y * 128;
  const int tileN = blockIdx.x * 128;

  const int tid  = threadIdx.x;
  const int wave = tid >> 6, lane = tid & 63;
  const int wm = (wave >> 1) * 64, wn = (wave & 1) * 64;
  const int quad = lane >> 4, lrow = lane & 15;

  f32x4 acc[4][4] = {};

  // batch-aware operand row bases (tiles never straddle batches: S%128==0)
  size_t rowA = tileM, rowB = tileN;
  if (MODE == 2) rowB = (size_t)(tileM >> 12) * S + tileN;  // Kh row = b*S + k
  if (MODE == 3) rowB = (size_t)(tileM >> 12) * H + tileN;  // Vt row = b*H + h
  const f16* gA = A + rowA * lda;
  const f16* gB = Bm + rowB * ldb;

  // staging: 128 rows x 8 chunks(16B); chunk stored at source col (c ^ (r&7))
  size_t aoff[4], boff[4];
  int ldsoff[4];
#pragma unroll
  for (int j = 0; j < 4; ++j) {
    int id = j * 256 + tid;
    int r = id >> 3, cs = (id & 7) ^ (r & 7);
    aoff[j] = (size_t)r * lda + cs * 8;
    boff[j] = (size_t)r * ldb + cs * 8;
    ldsoff[j] = id * 8;
  }

  for (int k0 = 0; k0 < K; k0 += 64) {
#pragma unroll
    for (int j = 0; j < 4; ++j) {
      GLD16(gA + aoff[j] + k0, &sA[ldsoff[j]]);
      GLD16(gB + boff[j] + k0, &sB[ldsoff[j]]);
    }
    __syncthreads();
#pragma unroll
    for (int kk = 0; kk < 2; ++kk) {
      f16x8 af[4], bf[4];
      const int ch = kk * 4 + quad;
      const int pos = (ch ^ (lrow & 7)) * 8;  // xor-unswizzle (row&7 == lrow&7)
#pragma unroll
      for (int x = 0; x < 4; ++x) {
        af[x] = *reinterpret_cast<const f16x8*>(&sA[(wm + x * 16 + lrow) * 64 + pos]);
        bf[x] = *reinterpret_cast<const f16x8*>(&sB[(wn + x * 16 + lrow) * 64 + pos]);
      }
#pragma unroll
      for (int x = 0; x < 4; ++x)
#pragma unroll
        for (int y = 0; y < 4; ++y)
          acc[x][y] = __builtin_amdgcn_mfma_f32_16x16x32_f16(af[x], bf[y], acc[x][y], 0, 0, 0);
    }
    __syncthreads();
  }

  // ---- V epilogue (MODE 0, seg==2): bounce through LDS for coalesced stores
  if (MODE == 0 && (tileN >> 11) == 2) {
    const int nn0 = tileN - 2 * H;              // V column base
    const int b = tileM >> 12, s0 = tileM & (S - 1);
    f16* sT = (f16*)smem;                       // [col][row], stride 136
#pragma unroll
    for (int x = 0; x < 4; ++x)
#pragma unroll
      for (int y = 0; y < 4; ++y) {
        int col = wn + y * 16 + lrow;
        int row = wm + x * 16 + quad * 4;
        float bias = x2[nn0 + col];
        f16x4 h4 = {(f16)(acc[x][y][0] + bias), (f16)(acc[x][y][1] + bias),
                    (f16)(acc[x][y][2] + bias), (f16)(acc[x][y][3] + bias)};
        *reinterpret_cast<f16x4*>(&sT[col * 136 + row]) = h4;
      }
    __syncthreads();
    const int c = tid >> 1, hh = tid & 1;
    const f16* src = &sT[c * 136 + hh * 64];
    f16* dst = (f16*)C2 + (size_t)b * H * S + (size_t)(nn0 + c) * S + s0 + hh * 64;
#pragma unroll
    for (int j = 0; j < 8; ++j)
      reinterpret_cast<f16x8*>(dst)[j] = reinterpret_cast<const f16x8*>(src)[j];
    return;
  }

#pragma unroll
  for (int x = 0; x < 4; ++x)
#pragma unroll
    for (int y = 0; y < 4; ++y)
#pragma unroll
      for (int r = 0; r < 4; ++r) {
        int m = tileM + wm + x * 16 + quad * 4 + r;
        int n = tileN + wn + y * 16 + lrow;
        float v = acc[x][y][r];
        if (MODE == 0) {
          int seg = n >> 11, nn = n & 2047;  // uniform per tile; seg 0/1 only here
          if (seg == 0) {
            ((f16*)C0)[(size_t)m * H + nn] = (f16)(v + x0[nn]);
          } else {
            ((f16*)C1)[(size_t)m * H + nn] = (f16)(v + x1[nn]);
          }
        } else if (MODE == 2) {
          int b = m >> 12;
          ((f16*)C0)[(size_t)m * S + n] = (f16)(v * scale + x0[(size_t)b * S + n]);
        } else {
          ((float*)C0)[(size_t)m * H + n] = v;
        }
      }
}

// ------------------------------------------------- softmax over 4096 f16, in place
__global__ __launch_bounds__(256) void softmax_f16(f16* __restrict__ sc) {
  const int tid = threadIdx.x;
  f16* rp = sc + (size_t)blockIdx.x * S;
  f16x8 h[2];
#pragma unroll
  for (int j = 0; j < 2; ++j) h[j] = reinterpret_cast<f16x8*>(rp)[tid + j * 256];

  float v[16];
#pragma unroll
  for (int j = 0; j < 2; ++j)
#pragma unroll
    for (int e = 0; e < 8; ++e) v[j * 8 + e] = (float)h[j][e];

  float m = -1e30f;
#pragma unroll
  for (int e = 0; e < 16; ++e) m = fmaxf(m, v[e]);
#pragma unroll
  for (int off = 32; off; off >>= 1) m = fmaxf(m, __shfl_xor(m, off));

  __shared__ float red[8];
  int wave = tid >> 6, lane = tid & 63;
  if (lane == 0) red[wave] = m;
  __syncthreads();
  m = fmaxf(fmaxf(red[0], red[1]), fmaxf(red[2], red[3]));

  float s = 0.f;
#pragma unroll
  for (int e = 0; e < 16; ++e) { v[e] = __expf(v[e] - m); s += v[e]; }
#pragma unroll
  for (int off = 32; off; off >>= 1) s += __shfl_xor(s, off);
  if (lane == 0) red[4 + wave] = s;
  __syncthreads();
  s = red[4] + red[5] + red[6] + red[7];
  float inv = 1.0f / s;

#pragma unroll
  for (int j = 0; j < 2; ++j) {
#pragma unroll
    for (int e = 0; e < 8; ++e) h[j][e] = (f16)(v[j * 8 + e] * inv);
    reinterpret_cast<f16x8*>(rp)[tid + j * 256] = h[j];
  }
}

// ---------------------------------------------------------------- launch
extern "C" void kernel_launch(void* const* d_in, const int* in_sizes, int n_in,
                              void* d_out, int out_size, void* d_ws, size_t ws_size,
                              hipStream_t stream) {
  const float* hs   = (const float*)d_in[0];
  const float* mask = (const float*)d_in[1];
  const float* Wq   = (const float*)d_in[2];
  const float* bq   = (const float*)d_in[3];
  const float* Wk   = (const float*)d_in[4];
  const float* bk   = (const float*)d_in[5];
  const float* Wv   = (const float*)d_in[6];
  const float* bv   = (const float*)d_in[7];
  float* out = (float*)d_out;

  // workspace layout (~226 MB)
  f16* hs_h = (f16*)d_ws;                        // B*S*H
  f16* w_h  = hs_h + (size_t)B * S * H;          // 3*H*H concat
  f16* Qh   = w_h + (size_t)3 * H * H;           // B*S*H
  f16* Kh   = Qh + (size_t)B * S * H;            // B*S*H
  f16* Vt   = Kh + (size_t)B * S * H;            // B*H*S (transposed)
  f16* Sc   = Vt + (size_t)B * S * H;            // B*S*S f16

  const int castN = B * S * H / 4 + 3 * H * H / 4;  // 7,340,032
  cast_all<<<(castN + 255) / 256, 256, 0, stream>>>(hs, Wq, Wk, Wv, hs_h, w_h);

  dim3 blk(256);
  const float sscale = 0.088388347648318447f;  // 1/sqrt(HEAD_SIZE=128)

  // fused QKV: M=8192, N=6144, K=2048. grid (48,64), x fastest
  gemm_tn<0><<<dim3(48, 64), blk, 0, stream>>>(
      hs_h, w_h, Qh, Kh, Vt, bq, bk, bv, 1.f, H, H, H);

  // scores both batches: M=8192, N=4096, K=2048. grid (32,64)
  gemm_tn<2><<<dim3(32, 64), blk, 0, stream>>>(
      Qh, Kh, Sc, nullptr, nullptr, mask, nullptr, nullptr, sscale, H, H, H);

  softmax_f16<<<B * S, 256, 0, stream>>>(Sc);

  // PV both batches: M=8192, N=2048, K=4096. grid (16,64)
  gemm_tn<3><<<dim3(16, 64), blk, 0, stream>>>(
      Sc, Vt, out, nullptr, nullptr, nullptr, nullptr, nullptr, 1.f, S, S, S);
}